// Round 10
// baseline (133.070 us; speedup 1.0000x reference)
//
#include <hip/hip_runtime.h>

#define N_   8
#define D_   64
#define H_   64
#define W_   64
#define HW_  (H_ * W_)
#define KK   25
#define NBLK 256   // grid size; <= 256 CUs -> all blocks co-resident

// ---------------------------------------------------------------------------
// Single fused FeatureAlign kernel (R6's best-measured structure + in-kernel
// counting + manual device-scope grid barrier).
//
// Key algebra: normalized weights w_k = relu(s_k)/sum relu(s_j) are
// scale-invariant; global nonzero counts are needed ONLY for the zero-mass
// test. So Phase A computes window dots AND nonzero partial counts from loads
// it already performs (cur center c, prev center t[2][1] -- each element
// covered exactly once across the grid), publishes per-block partials with
// agent-scope stores, then all blocks sync on a device-scope barrier counter
// (release add + acquire spin by thread 0; co-residency guaranteed: 256
// blocks on 256 CUs, 8 waves, 51.2 KB LDS each). Phase B = weights + output.
//
// Grid: 256 = (n = b>>5, y-pair = b&31). Block: 512 thr = 8 waves = 8
// channel-groups; lane = (row r, xq): 2 rows x 32 float2 pixel-pairs.
// ---------------------------------------------------------------------------
__global__ __launch_bounds__(512, 1) void feature_align_fused(
    const float* __restrict__ cur, const float* __restrict__ prev,
    const float* __restrict__ pm, float* __restrict__ out,
    unsigned int* __restrict__ pc, unsigned int* __restrict__ pq,
    unsigned int* __restrict__ bar)
{
    __shared__ float red[4][KK][128];   // 51.2 KB; aliased: red[0]=wght, red[1][0]=zflag
    __shared__ unsigned int swc[8];     // per-wave packed count partials

    const int b    = blockIdx.x;                 // 0..255
    const int n    = b >> 5;                     // batch
    const int y0   = (b & 31) * 2;               // row pair
    const int tid  = threadIdx.x;
    const int lane = tid & 63;
    const int dg   = __builtin_amdgcn_readfirstlane(tid >> 6); // 0..7, wave-uniform
    const int r    = lane >> 5;                  // row within pair
    const int xq   = lane & 31;
    const int x0   = xq * 2;
    const int y    = y0 + r;
    const int pix0 = r * 64 + x0;                // pixel index in block [0,128)

    // d-invariant per-lane byte offsets.
    int cb[3];
#pragma unroll
    for (int i = 0; i < 3; ++i)
        cb[i] = min(max(x0 - 2 + 2 * i, 0), W_ - 2);     // even -> 8B aligned
    unsigned voff[5][3];
#pragma unroll
    for (int ky = 0; ky < 5; ++ky) {
        int qy = min(max(y + ky - 2, 0), H_ - 1);
#pragma unroll
        for (int i = 0; i < 3; ++i)
            voff[ky][i] = (unsigned)((qy * W_ + cb[i]) * 4);
    }
    const unsigned curoff = (unsigned)((y * W_ + x0) * 4);

    const size_t nbase = (size_t)n * D_ * HW_;
    const char* curb  = (const char*)(cur  + nbase + (size_t)dg * 8 * HW_);
    const char* prevb = (const char*)(prev + nbase + (size_t)dg * 8 * HW_);
    const char* pmb   = (const char*)(pm   + nbase + (size_t)dg * 8 * HW_);
    char*       outb  = (char*)(out + nbase + (size_t)dg * 8 * HW_);

    // ---- EARLY prefetch: pm centers (8 ch), overlapped with dot phase ----
    float2 pmc[8];
#pragma unroll
    for (int dd = 0; dd < 8; ++dd)
        pmc[dd] = *(const float2*)(pmb + (size_t)dd * HW_ * 4 + curoff);

    float acc0[KK], acc1[KK];
#pragma unroll
    for (int k = 0; k < KK; ++k) { acc0[k] = 0.f; acc1[k] = 0.f; }

    // ---- dot phase: 8 channels/thread, contiguous float2 loads + counting --
    unsigned int wc = 0, wp = 0;     // nonzero counts (<=16 each)
#pragma unroll
    for (int dd = 0; dd < 8; ++dd) {
        const char* cch = curb  + (size_t)dd * HW_ * 4;
        const char* pch = prevb + (size_t)dd * HW_ * 4;
        float2 c = *(const float2*)(cch + curoff);
        float2 t[5][3];
#pragma unroll
        for (int ky = 0; ky < 5; ++ky)
#pragma unroll
            for (int i = 0; i < 3; ++i)
                t[ky][i] = *(const float2*)(pch + voff[ky][i]);
        // exact-coverage counting: cur center + prev center (t[2][1] is
        // prev[ch][y][x0..x0+1]: qy[2]=y and cb[1]=x0, always unclamped)
        wc += (c.x != 0.f) + (c.y != 0.f);
        wp += (t[2][1].x != 0.f) + (t[2][1].y != 0.f);
#pragma unroll
        for (int ky = 0; ky < 5; ++ky) {
            float v[6] = { t[ky][0].x, t[ky][0].y, t[ky][1].x,
                           t[ky][1].y, t[ky][2].x, t[ky][2].y };
#pragma unroll
            for (int kx = 0; kx < 5; ++kx) {
                acc0[ky * 5 + kx] = fmaf(c.x, v[kx],     acc0[ky * 5 + kx]);
                acc1[ky * 5 + kx] = fmaf(c.y, v[kx + 1], acc1[ky * 5 + kx]);
            }
        }
    }

    // ---- wave-reduce packed counts; leaders publish to LDS ----
    unsigned int pk = wc | (wp << 16);           // wave sum <=1024 per field
#pragma unroll
    for (int st = 32; st >= 1; st >>= 1)
        pk += __shfl_xor(pk, st);
    if (lane == 0) swc[dg] = pk;

    // ---- cross-group reduction: waves 0-3 write; waves 4-7 add ----
    if (dg < 4) {
#pragma unroll
        for (int k = 0; k < KK; ++k)
            *(float2*)&red[dg][k][pix0] = make_float2(acc0[k], acc1[k]);
    }
    __syncthreads();
    if (dg >= 4) {
#pragma unroll
        for (int k = 0; k < KK; ++k) {
            float2 t2 = *(float2*)&red[dg - 4][k][pix0];
            t2.x += acc0[k]; t2.y += acc1[k];
            *(float2*)&red[dg - 4][k][pix0] = t2;
        }
    }

    // ---- thread 0 (dg=0, idle here): publish block partials, grid barrier --
    if (tid == 0) {
        unsigned int s = 0;
#pragma unroll
        for (int w = 0; w < 8; ++w) s += swc[w];   // block sums <=8192/field
        __hip_atomic_store(&pc[b], s & 0xFFFFu, __ATOMIC_RELAXED,
                           __HIP_MEMORY_SCOPE_AGENT);
        __hip_atomic_store(&pq[b], s >> 16, __ATOMIC_RELAXED,
                           __HIP_MEMORY_SCOPE_AGENT);
        __hip_atomic_fetch_add(bar, 1u, __ATOMIC_RELEASE,
                               __HIP_MEMORY_SCOPE_AGENT);
        while (__hip_atomic_load(bar, __ATOMIC_ACQUIRE,
                                 __HIP_MEMORY_SCOPE_AGENT) < NBLK)
            __builtin_amdgcn_s_sleep(2);
    }
    __syncthreads();   // all waves join; red reduction + global counts ready

    // ---- weights: first 128 threads, one pixel each ----
    if (tid < 128) {
        const int pix = tid;
        const int rr  = pix >> 6;
        const int xx  = pix & 63;
        const int l64 = tid & 63;

        // batch n's 32 block-partials, reduced across the wave
        unsigned int cc = 0, vv = 0;
        if (l64 < 32) {
            cc = __hip_atomic_load(&pc[(n << 5) + l64], __ATOMIC_RELAXED,
                                   __HIP_MEMORY_SCOPE_AGENT);
            vv = __hip_atomic_load(&pq[(n << 5) + l64], __ATOMIC_RELAXED,
                                   __HIP_MEMORY_SCOPE_AGENT);
        }
#pragma unroll
        for (int st = 32; st >= 1; st >>= 1) {
            cc += __shfl_xor(cc, st);
            vv += __shfl_xor(vv, st);
        }
        float scale = 1.0f / (((float)cc + 1e-8f) * ((float)vv + 1e-8f));

        float mass = 0.f;
        float cf[KK];
#pragma unroll
        for (int k = 0; k < KK; ++k) {
            float sm = red[0][k][pix] + red[1][k][pix]
                     + red[2][k][pix] + red[3][k][pix];
            int ky = k / 5, kx = k % 5;
            int py  = y0 + rr + ky - 2;
            int pxc = xx + kx - 2;
            bool val = (py >= 0) && (py < H_) && (pxc >= 0) && (pxc < W_);
            float c = val ? fmaxf(sm * scale, 0.f) : 0.f;
            cf[k] = c;
            mass += c;
        }
        bool  zero = fabsf(mass) < 1e-7f;
        float inv  = zero ? 0.f : 1.0f / mass;
        // Column pix only touched by this thread -> alias-safe rewrite.
#pragma unroll
        for (int k = 0; k < KK; ++k) red[0][k][pix] = cf[k] * inv;  // wght
        red[1][0][pix] = zero ? 1.f : 0.f;                          // zflag
    }
    __syncthreads();

    // ---- output phase ----
    const float zf0 = red[1][0][pix0];
    const float zf1 = red[1][0][pix0 + 1];

    if (zf0 != 0.f && zf1 != 0.f) {
        // Hot path: pure stores of prefetched pm centers.
#pragma unroll
        for (int dd = 0; dd < 8; ++dd)
            *(float2*)(outb + (size_t)dd * HW_ * 4 + curoff) = pmc[dd];
    } else {
        // Cold path (correctness only on this data).
        float w0[KK], w1[KK];
#pragma unroll
        for (int k = 0; k < KK; ++k) {
            float2 ww = *(float2*)&red[0][k][pix0];
            w0[k] = ww.x; w1[k] = ww.y;
        }
#pragma unroll
        for (int dd = 0; dd < 8; ++dd) {
            const char* pch = pmb + (size_t)dd * HW_ * 4;
            float2 t2[5][3];
#pragma unroll
            for (int ky = 0; ky < 5; ++ky)
#pragma unroll
                for (int i = 0; i < 3; ++i)
                    t2[ky][i] = *(const float2*)(pch + voff[ky][i]);
            float v0 = 0.f, v1 = 0.f;
#pragma unroll
            for (int ky = 0; ky < 5; ++ky) {
                float v[6] = { t2[ky][0].x, t2[ky][0].y, t2[ky][1].x,
                               t2[ky][1].y, t2[ky][2].x, t2[ky][2].y };
#pragma unroll
                for (int kx = 0; kx < 5; ++kx) {
                    v0 = fmaf(w0[ky * 5 + kx], v[kx],     v0);
                    v1 = fmaf(w1[ky * 5 + kx], v[kx + 1], v1);
                }
            }
            float2 o;
            o.x = (zf0 != 0.f) ? pmc[dd].x : v0;
            o.y = (zf1 != 0.f) ? pmc[dd].y : v1;
            *(float2*)(outb + (size_t)dd * HW_ * 4 + curoff) = o;
        }
    }
}

extern "C" void kernel_launch(void* const* d_in, const int* in_sizes, int n_in,
                              void* d_out, int out_size, void* d_ws, size_t ws_size,
                              hipStream_t stream)
{
    const float* cur  = (const float*)d_in[0];
    const float* prev = (const float*)d_in[1];
    const float* pm   = (const float*)d_in[2];
    float*       out  = (float*)d_out;
    unsigned int* pc  = (unsigned int*)d_ws;        // 256 partials (cur)
    unsigned int* pq  = pc + NBLK;                  // 256 partials (prev)
    unsigned int* bar = pq + NBLK;                  // grid-barrier counter

    // ws is re-poisoned to 0xAA before every timed launch -> zero the barrier.
    hipMemsetAsync(bar, 0, sizeof(unsigned int), stream);

    feature_align_fused<<<NBLK, 512, 0, stream>>>(cur, prev, pm, out, pc, pq, bar);
}

// Round 11
// 89.370 us; speedup vs baseline: 1.4890x; 1.4890x over previous
//
#include <hip/hip_runtime.h>

#define N_  8
#define D_  64
#define H_  64
#define W_  64
#define HW_ (H_ * W_)
#define KK  25

// ---------------------------------------------------------------------------
// Kernel 1: per-block nonzero partial counts of cur and prev; also streams
// prev_mem (partials to pr, never consumed) to warm L3 for kernel 2.
// 512 blocks x 256 threads, 4096 elems/block, 64 blocks per batch. (Proven.)
// ---------------------------------------------------------------------------
__global__ __launch_bounds__(256) void count_nz_kernel(
    const float4* __restrict__ cur, const float4* __restrict__ prev,
    const float4* __restrict__ pmv,
    unsigned int* __restrict__ pc, unsigned int* __restrict__ pq,
    unsigned int* __restrict__ pr)
{
    __shared__ unsigned int sc[4], sp[4], sr[4];
    const int t    = threadIdx.x;
    const int wid  = t >> 6;
    const int lane = t & 63;

    unsigned int wc = 0, wp = 0, wr = 0;
#pragma unroll
    for (int j = 0; j < 4; ++j) {
        int idx = blockIdx.x * 1024 + j * 256 + t;
        float4 a = cur[idx];
        float4 b = prev[idx];
        float4 m = pmv[idx];
        wc += (unsigned)__popcll(__ballot(a.x != 0.f));
        wc += (unsigned)__popcll(__ballot(a.y != 0.f));
        wc += (unsigned)__popcll(__ballot(a.z != 0.f));
        wc += (unsigned)__popcll(__ballot(a.w != 0.f));
        wp += (unsigned)__popcll(__ballot(b.x != 0.f));
        wp += (unsigned)__popcll(__ballot(b.y != 0.f));
        wp += (unsigned)__popcll(__ballot(b.z != 0.f));
        wp += (unsigned)__popcll(__ballot(b.w != 0.f));
        wr += (unsigned)__popcll(__ballot(m.x != 0.f));
        wr += (unsigned)__popcll(__ballot(m.y != 0.f));
        wr += (unsigned)__popcll(__ballot(m.z != 0.f));
        wr += (unsigned)__popcll(__ballot(m.w != 0.f));
    }
    if (lane == 0) { sc[wid] = wc; sp[wid] = wp; sr[wid] = wr; }
    __syncthreads();
    if (t == 0) {
        pc[blockIdx.x] = sc[0] + sc[1] + sc[2] + sc[3];
        pq[blockIdx.x] = sp[0] + sp[1] + sp[2] + sp[3];
        pr[blockIdx.x] = sr[0] + sr[1] + sr[2] + sr[3];
    }
}

// ---------------------------------------------------------------------------
// Kernel 2: fused FeatureAlign = R6's best-measured structure, with the spill
// fixed: amdgpu_waves_per_eu(2,2) pins the only feasible occupancy (8-wave
// block -> 2 waves/SIMD) so the allocator gets the full 256-VGPR budget.
// (R10's counters proved the 128-VGPR heuristic allocation spills ~57 MB of
// scratch per dispatch: WRITE_SIZE 65.5 MB vs 8.4 MB of actual output.)
// Output stores are nontemporal (write-only data, keep L2 clean for reads).
//
// Grid: 256 = (n, y-pair). Block: 512 thr = 8 waves = 8 ch-groups; lane =
// (row r, xq): 2 rows x 32 float2 pixel-pairs. Phases: early prefetch (pm
// centers + counts) -> dot (contiguous float2 loads) -> LDS cross-group
// reduce -> weights (128 threads) -> output.
// ---------------------------------------------------------------------------
__global__
__attribute__((amdgpu_flat_work_group_size(512, 512), amdgpu_waves_per_eu(2, 2)))
void feature_align_kernel(
    const float* __restrict__ cur, const float* __restrict__ prev,
    const float* __restrict__ pm, float* __restrict__ out,
    const unsigned int* __restrict__ pc, const unsigned int* __restrict__ pq)
{
    __shared__ float red[4][KK][128];   // 51.2 KB; aliased later: red[0]=wght, red[1][0]=zflag

    const int b    = blockIdx.x;                 // 0..255
    const int n    = b >> 5;                     // batch
    const int y0   = (b & 31) * 2;               // row pair
    const int lane = threadIdx.x & 63;
    const int dg   = __builtin_amdgcn_readfirstlane(threadIdx.x >> 6); // 0..7
    const int r    = lane >> 5;                  // row within pair
    const int xq   = lane & 31;
    const int x0   = xq * 2;
    const int y    = y0 + r;
    const int pix0 = r * 64 + x0;                // pixel index in block [0,128)

    // d-invariant per-lane byte offsets.
    int cb[3];
#pragma unroll
    for (int i = 0; i < 3; ++i)
        cb[i] = min(max(x0 - 2 + 2 * i, 0), W_ - 2);     // even -> 8B aligned
    unsigned voff[5][3];
#pragma unroll
    for (int ky = 0; ky < 5; ++ky) {
        int qy = min(max(y + ky - 2, 0), H_ - 1);
#pragma unroll
        for (int i = 0; i < 3; ++i)
            voff[ky][i] = (unsigned)((qy * W_ + cb[i]) * 4);
    }
    const unsigned curoff = (unsigned)((y * W_ + x0) * 4);

    const size_t nbase = (size_t)n * D_ * HW_;
    const char* curb  = (const char*)(cur  + nbase + (size_t)dg * 8 * HW_);
    const char* prevb = (const char*)(prev + nbase + (size_t)dg * 8 * HW_);
    const char* pmb   = (const char*)(pm   + nbase + (size_t)dg * 8 * HW_);
    char*       outb  = (char*)(out + nbase + (size_t)dg * 8 * HW_);

    // ---- EARLY prefetch: pm centers + count partials (off critical path) ----
    float2 pmc[8];
#pragma unroll
    for (int dd = 0; dd < 8; ++dd)
        pmc[dd] = *(const float2*)(pmb + (size_t)dd * HW_ * 4 + curoff);
    unsigned int ccnt = pc[(n << 6) + lane];
    unsigned int vcnt = pq[(n << 6) + lane];

    float acc0[KK], acc1[KK];
#pragma unroll
    for (int k = 0; k < KK; ++k) { acc0[k] = 0.f; acc1[k] = 0.f; }

    // ---- dot-product phase: 8 channels, contiguous float2 loads ----
#pragma unroll
    for (int dd = 0; dd < 8; ++dd) {
        const char* cch = curb  + (size_t)dd * HW_ * 4;
        const char* pch = prevb + (size_t)dd * HW_ * 4;
        float2 c = *(const float2*)(cch + curoff);
        float2 t[5][3];
#pragma unroll
        for (int ky = 0; ky < 5; ++ky)
#pragma unroll
            for (int i = 0; i < 3; ++i)
                t[ky][i] = *(const float2*)(pch + voff[ky][i]);
#pragma unroll
        for (int ky = 0; ky < 5; ++ky) {
            float v[6] = { t[ky][0].x, t[ky][0].y, t[ky][1].x,
                           t[ky][1].y, t[ky][2].x, t[ky][2].y };
#pragma unroll
            for (int kx = 0; kx < 5; ++kx) {
                acc0[ky * 5 + kx] = fmaf(c.x, v[kx],     acc0[ky * 5 + kx]);
                acc1[ky * 5 + kx] = fmaf(c.y, v[kx + 1], acc1[ky * 5 + kx]);
            }
        }
    }

    // ---- cross-dg reduction: dg 0-3 write, dg 4-7 add in place ----
    if (dg < 4) {
#pragma unroll
        for (int k = 0; k < KK; ++k)
            *(float2*)&red[dg][k][pix0] = make_float2(acc0[k], acc1[k]);
    }
    __syncthreads();
    if (dg >= 4) {
#pragma unroll
        for (int k = 0; k < KK; ++k) {
            float2 t2 = *(float2*)&red[dg - 4][k][pix0];
            t2.x += acc0[k]; t2.y += acc1[k];
            *(float2*)&red[dg - 4][k][pix0] = t2;
        }
    }
    __syncthreads();

    // ---- weights: first 128 threads, one pixel each ----
    if (threadIdx.x < 128) {
        const int pix = threadIdx.x;
        const int rr  = pix >> 6;
        const int xx  = pix & 63;

        unsigned int cc = ccnt, vv = vcnt;
#pragma unroll
        for (int st = 32; st >= 1; st >>= 1) {
            cc += __shfl_xor(cc, st);
            vv += __shfl_xor(vv, st);
        }
        float scale = 1.0f / (((float)cc + 1e-8f) * ((float)vv + 1e-8f));

        float mass = 0.f;
        float cf[KK];
#pragma unroll
        for (int k = 0; k < KK; ++k) {
            float sm = red[0][k][pix] + red[1][k][pix]
                     + red[2][k][pix] + red[3][k][pix];
            int ky = k / 5, kx = k % 5;
            int py  = y0 + rr + ky - 2;
            int pxc = xx + kx - 2;
            bool val = (py >= 0) && (py < H_) && (pxc >= 0) && (pxc < W_);
            float c = val ? fmaxf(sm * scale, 0.f) : 0.f;
            cf[k] = c;
            mass += c;
        }
        bool  zero = fabsf(mass) < 1e-7f;
        float inv  = zero ? 0.f : 1.0f / mass;
        // Column pix only touched by this thread -> alias-safe rewrite.
#pragma unroll
        for (int k = 0; k < KK; ++k) red[0][k][pix] = cf[k] * inv;  // wght
        red[1][0][pix] = zero ? 1.f : 0.f;                          // zflag
    }
    __syncthreads();

    // ---- output phase ----
    const float zf0 = red[1][0][pix0];
    const float zf1 = red[1][0][pix0 + 1];

    if (zf0 != 0.f && zf1 != 0.f) {
        // Hot path: nontemporal stores of prefetched pm centers.
#pragma unroll
        for (int dd = 0; dd < 8; ++dd) {
            double dv;
            __builtin_memcpy(&dv, &pmc[dd], 8);
            __builtin_nontemporal_store(
                dv, (double*)(outb + (size_t)dd * HW_ * 4 + curoff));
        }
    } else {
        // Cold path (correctness only on this data).
        float w0[KK], w1[KK];
#pragma unroll
        for (int k = 0; k < KK; ++k) {
            float2 ww = *(float2*)&red[0][k][pix0];
            w0[k] = ww.x; w1[k] = ww.y;
        }
#pragma unroll
        for (int dd = 0; dd < 8; ++dd) {
            const char* pch = pmb + (size_t)dd * HW_ * 4;
            float2 t2[5][3];
#pragma unroll
            for (int ky = 0; ky < 5; ++ky)
#pragma unroll
                for (int i = 0; i < 3; ++i)
                    t2[ky][i] = *(const float2*)(pch + voff[ky][i]);
            float v0 = 0.f, v1 = 0.f;
#pragma unroll
            for (int ky = 0; ky < 5; ++ky) {
                float v[6] = { t2[ky][0].x, t2[ky][0].y, t2[ky][1].x,
                               t2[ky][1].y, t2[ky][2].x, t2[ky][2].y };
#pragma unroll
                for (int kx = 0; kx < 5; ++kx) {
                    v0 = fmaf(w0[ky * 5 + kx], v[kx],     v0);
                    v1 = fmaf(w1[ky * 5 + kx], v[kx + 1], v1);
                }
            }
            float2 o;
            o.x = (zf0 != 0.f) ? pmc[dd].x : v0;
            o.y = (zf1 != 0.f) ? pmc[dd].y : v1;
            double dv;
            __builtin_memcpy(&dv, &o, 8);
            __builtin_nontemporal_store(
                dv, (double*)(outb + (size_t)dd * HW_ * 4 + curoff));
        }
    }
}

extern "C" void kernel_launch(void* const* d_in, const int* in_sizes, int n_in,
                              void* d_out, int out_size, void* d_ws, size_t ws_size,
                              hipStream_t stream)
{
    const float* cur  = (const float*)d_in[0];
    const float* prev = (const float*)d_in[1];
    const float* pm   = (const float*)d_in[2];
    float*       out  = (float*)d_out;
    unsigned int* pc  = (unsigned int*)d_ws;        // 512 partials (cur)
    unsigned int* pq  = pc + 512;                   // 512 partials (prev)
    unsigned int* pr  = pq + 512;                   // 512 partials (pm, unused)

    count_nz_kernel<<<512, 256, 0, stream>>>(
        (const float4*)cur, (const float4*)prev, (const float4*)pm, pc, pq, pr);

    feature_align_kernel<<<256, 512, 0, stream>>>(cur, prev, pm, out, pc, pq);
}